// Round 6
// baseline (298.783 us; speedup 1.0000x reference)
//
#include <hip/hip_runtime.h>
#include <stdint.h>
#include <stddef.h>

#define BATCH 16
#define SEQ 2048
#define HDIM 256
#define SCHUNK 32
#define TTILE 128
#define NCHUNK 64            // SEQ / SCHUNK
#define TILE_U16 8192        // 16 KB tile (32 x 256 halves)
#define NTILES 1024          // BATCH * NCHUNK
#define PREBLK 2048          // 2 half-blocks per tile
#define KSTRIDE 260          // prepass fp32 staging row stride (bank stride 4)

typedef float f32x4 __attribute__((ext_vector_type(4)));
typedef float f32x16 __attribute__((ext_vector_type(16)));
typedef _Float16 f16x8 __attribute__((ext_vector_type(8)));
typedef __bf16 bf16x8 __attribute__((ext_vector_type(8)));
typedef unsigned short u16;
typedef u16 u16x8 __attribute__((ext_vector_type(8)));
typedef unsigned int u32;
typedef u32 u32x4 __attribute__((ext_vector_type(4)));
typedef const __attribute__((address_space(1))) u32* gp1_t;
typedef __attribute__((address_space(3))) u32* lp3_t;

static __device__ __forceinline__ u16 f2bf(float f) {
  union { float f; unsigned int u; } v; v.f = f;
  unsigned int u = v.u;
  unsigned int r = u + 0x7FFFu + ((u >> 16) & 1u);  // RNE
  return (u16)(r >> 16);
}

// ============================================================================
// Pre-pass (unchanged from round 3): enc [S,B,2H] fp32 -> fragment tiles:
//   KH (fp16):  [kb 0..15][lane(m,g)][j] = K[s=m][h=kb*16+g*8+j]   (QK A-op)
//   VT (bf16):  [ht*2+ka][lane][j]      = K[s=ka*16+g*8+j][h=ht*32+m] (PV B-op)
// ============================================================================
__global__ __launch_bounds__(256, 8)
void prepass_kernel(const float* __restrict__ e,
                    u16* __restrict__ KH, u16* __restrict__ VT) {
  __shared__ float Ks[16 * KSTRIDE];   // 16 rows only: 16,640 B
  const int tid = threadIdx.x;
  const int bid = blockIdx.x;
  const int h2  = bid & 1;             // which 16-row half of the chunk
  const int tb  = bid >> 1;            // tile id 0..1023
  const int b   = tb >> 6;
  const int ck  = tb & 63;
  const size_t tile = (size_t)tb * TILE_U16;
  const int r0 = h2 * 16;

  {
    int row = tid >> 4;                // 0..15
    int c16 = tid & 15;                // 0..15
    const float* src = e + ((size_t)(ck * SCHUNK + r0 + row) * BATCH + b) * (2 * HDIM);
#pragma unroll
    for (int u = 0; u < 4; ++u) {
      int col = c16 * 4 + 64 * u;
      float4 xa = *(const float4*)(src + col);
      float4 xb = *(const float4*)(src + col + HDIM);
      float4 s; s.x = xa.x + xb.x; s.y = xa.y + xb.y; s.z = xa.z + xb.z; s.w = xa.w + xb.w;
      *(float4*)&Ks[row * KSTRIDE + col] = s;
    }
  }
  __syncthreads();

  const int lane = tid & 63;
  const int w = tid >> 6;              // 0..3

  {
    int half = lane >> 5;
    int l5   = lane & 31;
    int lm   = l5 & 15;                // m - r0
    int g    = (l5 >> 4) & 1;
#pragma unroll
    for (int i = 0; i < 2; ++i) {
      int kb = w * 4 + i * 2 + half;
      const float* rp = &Ks[lm * KSTRIDE + kb * 16 + g * 8];
      u16x8 hi;
#pragma unroll
      for (int j = 0; j < 8; ++j)
        hi[j] = __builtin_bit_cast(u16, (_Float16)rp[j]);
      int lane_out = g * 32 + r0 + lm;
      *(u16x8*)&KH[tile + (size_t)(kb * 64 + lane_out) * 8] = hi;
    }
  }

  {
    int m = lane & 31;
    int g = lane >> 5;
#pragma unroll
    for (int i = 0; i < 2; ++i) {
      int ht = w * 2 + i;
      int fr = ht * 2 + h2;
      u16x8 v;
#pragma unroll
      for (int j = 0; j < 8; ++j)
        v[j] = f2bf(Ks[(g * 8 + j) * KSTRIDE + ht * 32 + m]);
      *(u16x8*)&VT[tile + (size_t)(fr * 64 + lane) * 8] = v;
    }
  }
}

// ============================================================================
// Main: 512 threads (8 waves). Source-split: waves 0-3 even chunks, 4-7 odd
// chunks, same 128 targets.
// Design E (pipe load-balancing):
//   V is NOT staged in LDS. Each wave loads its V fragments directly from
//   the workspace (contiguous 16 B/lane global_load_dwordx4, L2-resident
//   under the XCD swizzle) with a 2-ht register lookahead. LDS-pipe load
//   per iteration halves (V's 128 KB of ds_reads + 32 KB of gload_lds
//   writes move to the near-idle vector/L2 pipe). K path unchanged
//   (all 8 waves stage 4 KB each). LDS: 64 KB K + 1 KB dex -> possibly
//   2 blocks/CU now (133 KB < 160 KB).
//   Epilogue exchange runs in two ht-phases inside the K buffers.
// Carried from r3: T12 register-P (cvt_pk + permlane32_swap), one barrier
// per iteration, 2-deep K prefetch, XCD swizzle, __expf softmax.
// ============================================================================
__global__ __launch_bounds__(512, 2)
void attn_main_kernel(const u16* __restrict__ KH, const u16* __restrict__ VT,
                      const float* __restrict__ dq,  // [T, B, H]
                      float* __restrict__ out) {     // [T, B, H]
  __shared__ alignas(16) u16 KHs[4][TILE_U16];   // 64 KB : K pair-sets {0,1},{2,3}
  __shared__ float dex[256];                     // 1 KB : denom exchange

  const int tid  = threadIdx.x;
  const int lane = tid & 63;
  const int wv   = tid >> 6;        // 0..7
  const int wq   = wv & 3;          // target-group 0..3
  const int grp  = wv >> 2;         // 0 = even chunks, 1 = odd chunks
  const int m    = lane & 31;
  const int g    = lane >> 5;

  // XCD-aware swizzle: XCD x gets batches {2x, 2x+1}: ws set = 4MB ~= L2.
  const int bid = blockIdx.x;
  const int b  = ((bid & 7) << 1) | ((bid >> 3) & 1);
  const int t0 = (bid >> 4) * TTILE;

  // ---- Q fragments fp16 (B-operand: B[k=g*8+j][n=m]) ----
  const int tq = t0 + wq * 32 + m;
  const float* qp = dq + ((size_t)tq * BATCH + b) * HDIM;
  f16x8 qh[16];
#pragma unroll
  for (int kb = 0; kb < 16; ++kb) {
    int h = kb * 16 + g * 8;
    float4 f0 = *(const float4*)(qp + h);
    float4 f1 = *(const float4*)(qp + h + 4);
    float xs[8] = {f0.x, f0.y, f0.z, f0.w, f1.x, f1.y, f1.z, f1.w};
    u16x8 hb;
#pragma unroll
    for (int j = 0; j < 8; ++j)
      hb[j] = __builtin_bit_cast(u16, (_Float16)xs[j]);
    qh[kb] = __builtin_bit_cast(f16x8, hb);
  }

  f32x16 ctx[8];
#pragma unroll
  for (int ht = 0; ht < 8; ++ht) ctx[ht] = (f32x16)(0.0f);
  float dsum = 0.0f;
  bf16x8 pa0 = {}, pa1 = {};     // P fragments for the pending PV (registers)

  // ---- K staging: all 8 waves stage 4 KB of the pair's 32 KB ----
  // wave wv stages chunk 2p + (wv>>2), quarter (wv&3).
  auto stage = [&](int p) {                 // stage pair p (K only)
    int ck2   = 2 * p + (wv >> 2);
    int ktile = 2 * (p & 1) + (wv >> 2);    // K: 2 pair-sets
    size_t tb = ((size_t)b * NCHUNK + ck2) * TILE_U16;
    u16* dst = &KHs[ktile][0];
#pragma unroll
    for (int i = 0; i < 4; ++i) {
      int sub = (wv & 3) * 4 + i;
      __builtin_amdgcn_global_load_lds(
          (gp1_t)(const void*)&KH[tb + (size_t)sub * 512 + lane * 8],
          (lp3_t)(void*)&dst[sub * 512], 16, 0, 0);
    }
  };

  // QK^T as S^T (m=s, n=t) for pair p, fp16, two independent chains
  auto qk = [&](int p, f32x16& a0, f32x16& a1) {
    int kt = 2 * (p & 1) + grp;
#pragma unroll
    for (int kb = 0; kb < 16; kb += 2) {
      f16x8 k0 = __builtin_bit_cast(f16x8, *(const u16x8*)&KHs[kt][kb * 512 + lane * 8]);
      f16x8 k1 = __builtin_bit_cast(f16x8, *(const u16x8*)&KHs[kt][(kb + 1) * 512 + lane * 8]);
      a0 = __builtin_amdgcn_mfma_f32_32x32x16_f16(k0, qh[kb], a0, 0, 0, 0);
      a1 = __builtin_amdgcn_mfma_f32_32x32x16_f16(k1, qh[kb + 1], a1, 0, 0, 0);
    }
  };

  // exp(s-128) -> dsum; cvt_pk + permlane32_swap builds PV A-frags (T12).
  auto softmax_pack = [&](const f32x16& a0, const f32x16& a1) {
    float pf[16];
#pragma unroll
    for (int r = 0; r < 16; ++r) {
      pf[r] = __expf(a0[r] + a1[r] - 128.0f);
      dsum += pf[r];
    }
    u32 c[8];
#pragma unroll
    for (int q = 0; q < 8; ++q)
      asm("v_cvt_pk_bf16_f32 %0, %1, %2"
          : "=v"(c[q]) : "v"(pf[2 * q]), "v"(pf[2 * q + 1]));
    asm("v_permlane32_swap_b32 %0, %1" : "+v"(c[0]), "+v"(c[2]));
    asm("v_permlane32_swap_b32 %0, %1" : "+v"(c[1]), "+v"(c[3]));
    asm("v_permlane32_swap_b32 %0, %1" : "+v"(c[4]), "+v"(c[6]));
    asm("v_permlane32_swap_b32 %0, %1" : "+v"(c[5]), "+v"(c[7]));
    u32x4 w0 = {c[0], c[1], c[2], c[3]};
    u32x4 w1 = {c[4], c[5], c[6], c[7]};
    pa0 = __builtin_bit_cast(bf16x8, w0);
    pa1 = __builtin_bit_cast(bf16x8, w1);
  };

  // ---- prologue: stage K pairs 0,1; QK_0 + SM_0 ----
  stage(0);
  stage(1);
  asm volatile("s_waitcnt vmcnt(4)" ::: "memory");  // pair 0 landed; pair 1 flying
  __builtin_amdgcn_s_barrier();
  {
    f32x16 a0 = (f32x16)(0.0f), a1 = (f32x16)(0.0f);
    qk(0, a0, a1);
    softmax_pack(a0, a1);
  }

  // ---- main loop: one barrier per iter; V direct from L2 ----
  for (int j = 0; j < 32; ++j) {
    asm volatile("s_waitcnt vmcnt(0)" ::: "memory"); // K stage(j+1) landed
    __builtin_amdgcn_s_barrier();

    const int ckk = 2 * j + grp;     // this wave's chunk
    const u16* vb = VT + ((size_t)b * NCHUNK + ckk) * TILE_U16;

    // V register lookahead: preload ht 0,1 before QK (latency under QK)
    u16x8 vv0[8], vv1[8];
    vv0[0] = *(const u16x8*)&vb[(size_t)(0 * 64 + lane) * 8];
    vv1[0] = *(const u16x8*)&vb[(size_t)(1 * 64 + lane) * 8];
    vv0[1] = *(const u16x8*)&vb[(size_t)(2 * 64 + lane) * 8];
    vv1[1] = *(const u16x8*)&vb[(size_t)(3 * 64 + lane) * 8];

    if (j < 30) stage(j + 2);

    f32x16 a0 = (f32x16)(0.0f), a1 = (f32x16)(0.0f);
    __builtin_amdgcn_s_setprio(1);
    if (j < 31) qk(j + 1, a0, a1);   // independent of PV below

    // ---- PV: ctx(m=t, n=h) += P * V, V from global with 2-ht lookahead ----
#pragma unroll
    for (int ht = 0; ht < 8; ++ht) {
      if (ht < 6) {
        vv0[ht + 2] = *(const u16x8*)&vb[(size_t)((2 * ht + 4) * 64 + lane) * 8];
        vv1[ht + 2] = *(const u16x8*)&vb[(size_t)((2 * ht + 5) * 64 + lane) * 8];
      }
      bf16x8 v0 = __builtin_bit_cast(bf16x8, vv0[ht]);
      bf16x8 v1 = __builtin_bit_cast(bf16x8, vv1[ht]);
      ctx[ht] = __builtin_amdgcn_mfma_f32_32x32x16_bf16(pa0, v0, ctx[ht], 0, 0, 0);
      ctx[ht] = __builtin_amdgcn_mfma_f32_32x32x16_bf16(pa1, v1, ctx[ht], 0, 0, 0);
    }
    __builtin_amdgcn_s_setprio(0);

    if (j < 31) softmax_pack(a0, a1);  // overlaps in-flight PV MFMAs
  }

  // ---- combine the two source-halves (exact: same exp offset) ----
  dsum += __shfl_xor(dsum, 32, 64);   // per-lane: partial denom for t = m
  __syncthreads();                     // all K-loop LDS reads done

  // exchange region: 16 KB per target-group inside KHs (64 KB total);
  // two phases over ht halves.
  float* exch = (float*)&KHs[0][0] + wq * 4096;
  float inv = 0.0f;

#pragma unroll
  for (int ph = 0; ph < 2; ++ph) {
    if (grp == 1) {
#pragma unroll
      for (int r4 = 0; r4 < 4; ++r4)
#pragma unroll
        for (int hh = 0; hh < 4; ++hh) {
          int ht = ph * 4 + hh;
          f32x4 v = {ctx[ht][r4 * 4], ctx[ht][r4 * 4 + 1],
                     ctx[ht][r4 * 4 + 2], ctx[ht][r4 * 4 + 3]};
          *(f32x4*)&exch[r4 * 1024 + hh * 256 + lane * 4] = v;
        }
      if (ph == 0) dex[wq * 64 + lane] = dsum;
    }
    __syncthreads();
    if (grp == 0) {
      if (ph == 0) {
        float dB = dex[wq * 64 + lane];
        inv = 1.0f / (dsum + dB);
      }
#pragma unroll
      for (int r4 = 0; r4 < 4; ++r4)
#pragma unroll
        for (int hh = 0; hh < 4; ++hh) {
          int ht = ph * 4 + hh;
          f32x4 v = *(const f32x4*)&exch[r4 * 1024 + hh * 256 + lane * 4];
          ctx[ht][r4 * 4]     += v[0];
          ctx[ht][r4 * 4 + 1] += v[1];
          ctx[ht][r4 * 4 + 2] += v[2];
          ctx[ht][r4 * 4 + 3] += v[3];
        }
#pragma unroll
      for (int r = 0; r < 16; ++r) {
        int tl = (r & 3) + 8 * (r >> 2) + 4 * g;
        float rinv = __shfl(inv, tl, 64);
        int t = t0 + wq * 32 + tl;
        float* op = out + ((size_t)t * BATCH + b) * HDIM + m;
#pragma unroll
        for (int hh = 0; hh < 4; ++hh) {
          int ht = ph * 4 + hh;
          op[ht * 32] = ctx[ht][r] * rinv;
        }
      }
    }
    __syncthreads();
  }
}

extern "C" void kernel_launch(void* const* d_in, const int* in_sizes, int n_in,
                              void* d_out, int out_size, void* d_ws, size_t ws_size,
                              hipStream_t stream) {
  const float* e  = (const float*)d_in[0];  // out_e [2048, 16, 512]
  const float* dq = (const float*)d_in[1];  // out_d [2048, 16, 256]
  float* out = (float*)d_out;               // [2048, 16, 256]
  u16* KH = (u16*)d_ws;                                 // fp16 bits, 16 MB
  u16* VT = KH + (size_t)NTILES * TILE_U16;             // bf16 bits, 16 MB
  prepass_kernel<<<dim3(PREBLK), dim3(256), 0, stream>>>(e, KH, VT);
  attn_main_kernel<<<dim3(BATCH * (SEQ / TTILE)), dim3(512), 0, stream>>>(
      KH, VT, dq, out);
}

// Round 8
// 263.556 us; speedup vs baseline: 1.1337x; 1.1337x over previous
//
#include <hip/hip_runtime.h>
#include <stdint.h>
#include <stddef.h>

#define BATCH 16
#define SEQ 2048
#define HDIM 256
#define SCHUNK 32
#define TTILE 128
#define NCHUNK 64            // SEQ / SCHUNK
#define TILE_U16 8192        // 16 KB tile (32 x 256 halves)
#define NTILES 1024          // BATCH * NCHUNK
#define PREBLK 2048          // 2 half-blocks per tile
#define KSTRIDE 260          // prepass fp32 staging row stride (bank stride 4)

typedef float f32x4 __attribute__((ext_vector_type(4)));
typedef float f32x16 __attribute__((ext_vector_type(16)));
typedef _Float16 f16x8 __attribute__((ext_vector_type(8)));
typedef __bf16 bf16x8 __attribute__((ext_vector_type(8)));
typedef unsigned short u16;
typedef u16 u16x8 __attribute__((ext_vector_type(8)));
typedef unsigned int u32;
typedef u32 u32x4 __attribute__((ext_vector_type(4)));
typedef const __attribute__((address_space(1))) u32* gp1_t;
typedef __attribute__((address_space(3))) u32* lp3_t;

// Denominator accumulator [t][b] — static device memory, NOT in d_ws
// (round-7 audit: appending it to the 32 MB workspace may have overflowed
// ws_size; this removes the dependence entirely).
__device__ alignas(16) float g_den[SEQ * BATCH];

static __device__ __forceinline__ u16 f2bf(float f) {
  union { float f; unsigned int u; } v; v.f = f;
  unsigned int u = v.u;
  unsigned int r = u + 0x7FFFu + ((u >> 16) & 1u);  // RNE
  return (u16)(r >> 16);
}

// ============================================================================
// Zero-pass: out[8M f32] = 0, g_den = 0. (replaces hipMemsetAsync — keeps
// kernel_launch 100% graph-capture-safe)
// ============================================================================
__global__ __launch_bounds__(256, 8)
void zero_kernel(float* __restrict__ out) {
  int idx = blockIdx.x * 256 + threadIdx.x;     // f32x4 index
  ((f32x4*)out)[idx] = (f32x4)(0.0f);
  if (blockIdx.x < 32)                           // 32*256 = 8192 f32x4 = 32K f32
    ((f32x4*)g_den)[blockIdx.x * 256 + threadIdx.x] = (f32x4)(0.0f);
}

// ============================================================================
// Pre-pass (unchanged): enc [S,B,2H] fp32 -> fragment tiles:
//   KH (fp16):  [kb 0..15][lane(m,g)][j] = K[s=m][h=kb*16+g*8+j]   (QK A-op)
//   VT (bf16):  [ht*2+ka][lane][j]      = K[s=ka*16+g*8+j][h=ht*32+m] (PV B-op)
// ============================================================================
__global__ __launch_bounds__(256, 8)
void prepass_kernel(const float* __restrict__ e,
                    u16* __restrict__ KH, u16* __restrict__ VT) {
  __shared__ float Ks[16 * KSTRIDE];   // 16 rows only: 16,640 B
  const int tid = threadIdx.x;
  const int bid = blockIdx.x;
  const int h2  = bid & 1;             // which 16-row half of the chunk
  const int tb  = bid >> 1;            // tile id 0..1023
  const int b   = tb >> 6;
  const int ck  = tb & 63;
  const size_t tile = (size_t)tb * TILE_U16;
  const int r0 = h2 * 16;

  {
    int row = tid >> 4;                // 0..15
    int c16 = tid & 15;                // 0..15
    const float* src = e + ((size_t)(ck * SCHUNK + r0 + row) * BATCH + b) * (2 * HDIM);
#pragma unroll
    for (int u = 0; u < 4; ++u) {
      int col = c16 * 4 + 64 * u;
      float4 xa = *(const float4*)(src + col);
      float4 xb = *(const float4*)(src + col + HDIM);
      float4 s; s.x = xa.x + xb.x; s.y = xa.y + xb.y; s.z = xa.z + xb.z; s.w = xa.w + xb.w;
      *(float4*)&Ks[row * KSTRIDE + col] = s;
    }
  }
  __syncthreads();

  const int lane = tid & 63;
  const int w = tid >> 6;              // 0..3

  {
    int half = lane >> 5;
    int l5   = lane & 31;
    int lm   = l5 & 15;                // m - r0
    int g    = (l5 >> 4) & 1;
#pragma unroll
    for (int i = 0; i < 2; ++i) {
      int kb = w * 4 + i * 2 + half;
      const float* rp = &Ks[lm * KSTRIDE + kb * 16 + g * 8];
      u16x8 hi;
#pragma unroll
      for (int j = 0; j < 8; ++j)
        hi[j] = __builtin_bit_cast(u16, (_Float16)rp[j]);
      int lane_out = g * 32 + r0 + lm;
      *(u16x8*)&KH[tile + (size_t)(kb * 64 + lane_out) * 8] = hi;
    }
  }

  {
    int m = lane & 31;
    int g = lane >> 5;
#pragma unroll
    for (int i = 0; i < 2; ++i) {
      int ht = w * 2 + i;
      int fr = ht * 2 + h2;
      u16x8 v;
#pragma unroll
      for (int j = 0; j < 8; ++j)
        v[j] = f2bf(Ks[(g * 8 + j) * KSTRIDE + ht * 32 + m]);
      *(u16x8*)&VT[tile + (size_t)(fr * 64 + lane) * 8] = v;
    }
  }
}

// ============================================================================
// Main, S-SPLIT (design F): grid 512 = 16 b x 16 t-tiles x 2 source-halves;
// 256 threads (4 waves = 4 wq t-groups). Each block: 32 single chunks with
// the r3 cross-iteration pipeline (QK_{c+1} || PV_c, register-P, ONE
// barrier/iter, 2-ahead staging). LDS = K[2]+V[3] = 80 KB -> 2 blocks/CU
// with INDEPENDENT barriers (per-CU LDS traffic / MFMA identical to r3's
// 8-wave block; only the sync coupling changes). Halves combine via
// device-scope atomicAdd into zeroed out/g_den; divide_kernel normalizes.
// Staging split FIXED from r7: 8 subs per wave (K = wq0 subs 0-7 + wq1
// subs 8-15; V likewise for wq2/3) — r7's 16-sub version overran the tile.
// ============================================================================
__global__ __launch_bounds__(256, 2)
void attn_main_kernel(const u16* __restrict__ KH, const u16* __restrict__ VT,
                      const float* __restrict__ dq,  // [T, B, H]
                      float* __restrict__ out) {     // [T, B, H] (zeroed, accum)
  __shared__ alignas(16) u16 KHs[2][TILE_U16];   // 32 KB : K double-buffer
  __shared__ alignas(16) u16 VTs[3][TILE_U16];   // 48 KB : V rotate mod 3

  const int tid  = threadIdx.x;
  const int lane = tid & 63;
  const int wq   = tid >> 6;        // 0..3 target-group
  const int m    = lane & 31;
  const int g    = lane >> 5;

  // XCD-aware swizzle: XCD x gets batches {2x, 2x+1} (4 MB ~= L2).
  // bid bits: [2:0]=xcd, [3]=b_lo, [7:4]=t-tile, [8]=source half.
  const int bid = blockIdx.x;
  const int b  = ((bid & 7) << 1) | ((bid >> 3) & 1);
  const int t0 = ((bid >> 4) & 15) * TTILE;
  const int c0 = ((bid >> 8) & 1) * 32;      // this block's chunk base

  // ---- Q fragments fp16 (B-operand: B[k=g*8+j][n=m]) ----
  const int tq = t0 + wq * 32 + m;
  const float* qp = dq + ((size_t)tq * BATCH + b) * HDIM;
  f16x8 qh[16];
#pragma unroll
  for (int kb = 0; kb < 16; ++kb) {
    int h = kb * 16 + g * 8;
    float4 f0 = *(const float4*)(qp + h);
    float4 f1 = *(const float4*)(qp + h + 4);
    float xs[8] = {f0.x, f0.y, f0.z, f0.w, f1.x, f1.y, f1.z, f1.w};
    u16x8 hb;
#pragma unroll
    for (int j = 0; j < 8; ++j)
      hb[j] = __builtin_bit_cast(u16, (_Float16)xs[j]);
    qh[kb] = __builtin_bit_cast(f16x8, hb);
  }

  f32x16 ctx[8];
#pragma unroll
  for (int ht = 0; ht < 8; ++ht) ctx[ht] = (f32x16)(0.0f);
  float dsum = 0.0f;
  bf16x8 pa0 = {}, pa1 = {};     // P fragments for the pending PV (registers)

  // ---- staging: per chunk 32 KB (K 16 + V 16); wave wq stages 8 subs ----
  // wq 0: K subs 0-7 | wq 1: K subs 8-15 | wq 2: V subs 0-7 | wq 3: V 8-15
  const u16* srcArr = (wq < 2) ? KH : VT;
  const int  subbase = (wq & 1) * 8;
  auto stage = [&](int c) {                 // local chunk index
    int kset = c & 1, vset = c % 3;
    size_t tb = ((size_t)b * NCHUNK + c0 + c) * TILE_U16;
    u16* dst = (wq < 2) ? &KHs[kset][0] : &VTs[vset][0];
#pragma unroll
    for (int i = 0; i < 8; ++i) {
      int sub = subbase + i;
      __builtin_amdgcn_global_load_lds(
          (gp1_t)(const void*)&srcArr[tb + (size_t)sub * 512 + lane * 8],
          (lp3_t)(void*)&dst[sub * 512], 16, 0, 0);
    }
  };

  // QK^T as S^T (rows = s, cols = t) for chunk c, fp16, two indep chains
  auto qk = [&](int c, f32x16& a0, f32x16& a1) {
    int kt = c & 1;
#pragma unroll
    for (int kb = 0; kb < 16; kb += 2) {
      f16x8 k0 = __builtin_bit_cast(f16x8, *(const u16x8*)&KHs[kt][kb * 512 + lane * 8]);
      f16x8 k1 = __builtin_bit_cast(f16x8, *(const u16x8*)&KHs[kt][(kb + 1) * 512 + lane * 8]);
      a0 = __builtin_amdgcn_mfma_f32_32x32x16_f16(k0, qh[kb], a0, 0, 0, 0);
      a1 = __builtin_amdgcn_mfma_f32_32x32x16_f16(k1, qh[kb + 1], a1, 0, 0, 0);
    }
  };

  // PV for chunk c using register P fragments pa0/pa1
  auto pv = [&](int c) {
    int vt_ = c % 3;
#pragma unroll
    for (int ht = 0; ht < 8; ++ht) {
      bf16x8 v0 = __builtin_bit_cast(bf16x8, *(const u16x8*)&VTs[vt_][(ht * 2) * 512 + lane * 8]);
      bf16x8 v1 = __builtin_bit_cast(bf16x8, *(const u16x8*)&VTs[vt_][(ht * 2 + 1) * 512 + lane * 8]);
      ctx[ht] = __builtin_amdgcn_mfma_f32_32x32x16_bf16(pa0, v0, ctx[ht], 0, 0, 0);
      ctx[ht] = __builtin_amdgcn_mfma_f32_32x32x16_bf16(pa1, v1, ctx[ht], 0, 0, 0);
    }
  };

  // exp(s-128) -> dsum; cvt_pk + permlane32_swap builds PV A-frags (T12).
  auto softmax_pack = [&](const f32x16& a0, const f32x16& a1) {
    float pf[16];
#pragma unroll
    for (int r = 0; r < 16; ++r) {
      pf[r] = __expf(a0[r] + a1[r] - 128.0f);
      dsum += pf[r];
    }
    u32 c[8];
#pragma unroll
    for (int q = 0; q < 8; ++q)
      asm("v_cvt_pk_bf16_f32 %0, %1, %2"
          : "=v"(c[q]) : "v"(pf[2 * q]), "v"(pf[2 * q + 1]));
    asm("v_permlane32_swap_b32 %0, %1" : "+v"(c[0]), "+v"(c[2]));
    asm("v_permlane32_swap_b32 %0, %1" : "+v"(c[1]), "+v"(c[3]));
    asm("v_permlane32_swap_b32 %0, %1" : "+v"(c[4]), "+v"(c[6]));
    asm("v_permlane32_swap_b32 %0, %1" : "+v"(c[5]), "+v"(c[7]));
    u32x4 w0 = {c[0], c[1], c[2], c[3]};
    u32x4 w1 = {c[4], c[5], c[6], c[7]};
    pa0 = __builtin_bit_cast(bf16x8, w0);
    pa1 = __builtin_bit_cast(bf16x8, w1);
  };

  // ---- prologue: stage chunks 0,1; QK_0 + SM_0 ----
  stage(0);
  stage(1);
  asm volatile("s_waitcnt vmcnt(8)" ::: "memory");  // chunk 0 landed; 1 flying
  __builtin_amdgcn_s_barrier();
  {
    f32x16 a0 = (f32x16)(0.0f), a1 = (f32x16)(0.0f);
    qk(0, a0, a1);
    softmax_pack(a0, a1);
  }

  // ---- main loop: QK_{c+1} || PV_c, one barrier per iter ----
  for (int c = 0; c < 32; ++c) {
    asm volatile("s_waitcnt vmcnt(0)" ::: "memory"); // stage(c+1) landed
    __builtin_amdgcn_s_barrier();
    if (c < 30) stage(c + 2);

    f32x16 a0 = (f32x16)(0.0f), a1 = (f32x16)(0.0f);
    __builtin_amdgcn_s_setprio(1);
    if (c < 31) qk(c + 1, a0, a1);   // independent of PV below
    pv(c);                           // consumes pa0/pa1 from previous SM
    __builtin_amdgcn_s_setprio(0);
    if (c < 31) softmax_pack(a0, a1);  // overlaps in-flight PV MFMAs
  }

  // ---- epilogue: accumulate partials into out/g_den (atomic f32) ----
  dsum += __shfl_xor(dsum, 32, 64);   // per-lane: half-denominator for t = m
  if (lane < 32)
    atomicAdd(&g_den[(size_t)(t0 + wq * 32 + lane) * BATCH + b], dsum);
#pragma unroll
  for (int r = 0; r < 16; ++r) {
    int tl = (r & 3) + 8 * (r >> 2) + 4 * g;
    int t = t0 + wq * 32 + tl;
    float* op = out + ((size_t)t * BATCH + b) * HDIM + m;
#pragma unroll
    for (int ht = 0; ht < 8; ++ht)
      atomicAdd(op + ht * 32, ctx[ht][r]);
  }
}

// ============================================================================
// Normalize: out[t,b,h] /= g_den[t,b]. 8M f32 = 2M f32x4, one per thread.
// ============================================================================
__global__ __launch_bounds__(256, 8)
void divide_kernel(float* __restrict__ out) {
  int idx = blockIdx.x * 256 + threadIdx.x;   // f32x4 index
  f32x4 v = ((f32x4*)out)[idx];
  float inv = 1.0f / g_den[idx >> 6];         // (t*16+b) = (idx*4)>>8
  v[0] *= inv; v[1] *= inv; v[2] *= inv; v[3] *= inv;
  ((f32x4*)out)[idx] = v;
}

extern "C" void kernel_launch(void* const* d_in, const int* in_sizes, int n_in,
                              void* d_out, int out_size, void* d_ws, size_t ws_size,
                              hipStream_t stream) {
  const float* e  = (const float*)d_in[0];  // out_e [2048, 16, 512]
  const float* dq = (const float*)d_in[1];  // out_d [2048, 16, 256]
  float* out = (float*)d_out;               // [2048, 16, 256]
  u16* KH = (u16*)d_ws;                                 // fp16 bits, 16 MB
  u16* VT = KH + (size_t)NTILES * TILE_U16;             // bf16 bits, 16 MB

  zero_kernel<<<dim3(SEQ * BATCH * HDIM / 4 / 256), dim3(256), 0, stream>>>(out);
  prepass_kernel<<<dim3(PREBLK), dim3(256), 0, stream>>>(e, KH, VT);
  attn_main_kernel<<<dim3(BATCH * (SEQ / TTILE) * 2), dim3(256), 0, stream>>>(
      KH, VT, dq, out);
  divide_kernel<<<dim3(SEQ * BATCH * HDIM / 4 / 256), dim3(256), 0, stream>>>(out);
}

// Round 10
// 201.527 us; speedup vs baseline: 1.4826x; 1.3078x over previous
//
#include <hip/hip_runtime.h>
#include <stdint.h>
#include <stddef.h>

#define BATCH 16
#define SEQ 2048
#define HDIM 256
#define SCHUNK 32
#define TTILE 128
#define NCHUNK 64            // SEQ / SCHUNK
#define TILE_U16 8192        // 16 KB tile (32 x 256 halves)
#define NTILES 1024          // BATCH * NCHUNK
#define PREBLK 2048          // 2 half-blocks per tile
#define KSTRIDE 260          // prepass fp32 staging row stride (bank stride 4)

typedef float f32x4 __attribute__((ext_vector_type(4)));
typedef float f32x16 __attribute__((ext_vector_type(16)));
typedef _Float16 f16x8 __attribute__((ext_vector_type(8)));
typedef __bf16 bf16x8 __attribute__((ext_vector_type(8)));
typedef unsigned short u16;
typedef u16 u16x8 __attribute__((ext_vector_type(8)));
typedef unsigned int u32;
typedef u32 u32x4 __attribute__((ext_vector_type(4)));
typedef const __attribute__((address_space(1))) u32* gp1_t;
typedef __attribute__((address_space(3))) u32* lp3_t;

static __device__ __forceinline__ u16 f2bf(float f) {
  union { float f; unsigned int u; } v; v.f = f;
  unsigned int u = v.u;
  unsigned int r = u + 0x7FFFu + ((u >> 16) & 1u);  // RNE
  return (u16)(r >> 16);
}

// ============================================================================
// Pre-pass: enc [S,B,2H] fp32 -> fragment-ordered tiles per (b,chunk):
//   KH (fp16):  [kb 0..15][lane(m,g)][j] = K[s=m][h=kb*16+g*8+j]   (QK A-op)
//   VT (bf16):  [ht*2+ka][lane][j]      = K[s=ka*16+g*8+j][h=ht*32+m] (PV B-op)
// Each block handles HALF a tile (16 s-rows) -> 2048 blocks, 16.6 KB LDS.
// FIX (r9): __launch_bounds__(256,4) — the (256,8) used since r1 capped the
// allocator at 64 VGPR/wave and forced scratch spills (suspected cause of
// prepass running ~90 µs vs its 15 µs roofline). 128 VGPR, 4 blocks/CU.
// ============================================================================
__global__ __launch_bounds__(256, 4)
void prepass_kernel(const float* __restrict__ e,
                    u16* __restrict__ KH, u16* __restrict__ VT) {
  __shared__ float Ks[16 * KSTRIDE];   // 16 rows only: 16,640 B
  const int tid = threadIdx.x;
  const int bid = blockIdx.x;
  const int h2  = bid & 1;             // which 16-row half of the chunk
  const int tb  = bid >> 1;            // tile id 0..1023
  const int b   = tb >> 6;
  const int ck  = tb & 63;
  const size_t tile = (size_t)tb * TILE_U16;
  const int r0 = h2 * 16;

  {
    int row = tid >> 4;                // 0..15
    int c16 = tid & 15;                // 0..15
    const float* src = e + ((size_t)(ck * SCHUNK + r0 + row) * BATCH + b) * (2 * HDIM);
#pragma unroll
    for (int u = 0; u < 4; ++u) {
      int col = c16 * 4 + 64 * u;
      float4 xa = *(const float4*)(src + col);
      float4 xb = *(const float4*)(src + col + HDIM);
      float4 s; s.x = xa.x + xb.x; s.y = xa.y + xb.y; s.z = xa.z + xb.z; s.w = xa.w + xb.w;
      *(float4*)&Ks[row * KSTRIDE + col] = s;
    }
  }
  __syncthreads();

  const int lane = tid & 63;
  const int w = tid >> 6;              // 0..3

  // ---- KH: wave w covers kb = 4w + 2i + (lane>=32); block owns m in [r0,r0+16)
  {
    int half = lane >> 5;
    int l5   = lane & 31;
    int lm   = l5 & 15;                // m - r0
    int g    = (l5 >> 4) & 1;
#pragma unroll
    for (int i = 0; i < 2; ++i) {
      int kb = w * 4 + i * 2 + half;
      const float* rp = &Ks[lm * KSTRIDE + kb * 16 + g * 8];
      u16x8 hi;
#pragma unroll
      for (int j = 0; j < 8; ++j)
        hi[j] = __builtin_bit_cast(u16, (_Float16)rp[j]);
      int lane_out = g * 32 + r0 + lm;
      *(u16x8*)&KH[tile + (size_t)(kb * 64 + lane_out) * 8] = hi;
    }
  }

  // ---- VT: block owns exactly ka = h2; wave w covers ht = 2w + i
  {
    int m = lane & 31;
    int g = lane >> 5;
#pragma unroll
    for (int i = 0; i < 2; ++i) {
      int ht = w * 2 + i;
      int fr = ht * 2 + h2;
      u16x8 v;
#pragma unroll
      for (int j = 0; j < 8; ++j)
        v[j] = f2bf(Ks[(g * 8 + j) * KSTRIDE + ht * 32 + m]);
      *(u16x8*)&VT[tile + (size_t)(fr * 64 + lane) * 8] = v;
    }
  }
}

// ============================================================================
// Main (exact r3 revert — the 94 µs champion): 512 threads (8 waves,
// 1 block/CU). Source-split: waves 0-3 even chunks, 4-7 odd chunks, same
// 128 targets. T12 register-P (cvt_pk + permlane32_swap), cross-iteration
// pipeline QK_{j+1} || PV_j, ONE barrier per iteration, K 2 pair-sets +
// V 3 pair-sets (160 KiB LDS), XCD swizzle, exch epilogue (exact combine).
// ============================================================================
__global__ __launch_bounds__(512, 2)
void attn_main_kernel(const u16* __restrict__ KH, const u16* __restrict__ VT,
                      const float* __restrict__ dq,  // [T, B, H]
                      float* __restrict__ out) {     // [T, B, H]
  __shared__ alignas(16) u16 KHs[4][TILE_U16];   // 64 KB : K pair-sets {0,1},{2,3}
  __shared__ alignas(16) u16 VTs[6][TILE_U16];   // 96 KB : V pair-sets rotate mod 3

  const int tid  = threadIdx.x;
  const int lane = tid & 63;
  const int wv   = tid >> 6;        // 0..7
  const int wq   = wv & 3;          // target-group 0..3
  const int grp  = wv >> 2;         // 0 = even chunks, 1 = odd chunks
  const int m    = lane & 31;
  const int g    = lane >> 5;

  // XCD-aware swizzle: XCD x gets batches {2x, 2x+1}: K/V set = 4MB ~= L2.
  const int bid = blockIdx.x;
  const int b  = ((bid & 7) << 1) | ((bid >> 3) & 1);
  const int t0 = (bid >> 4) * TTILE;

  // ---- Q fragments fp16 (B-operand: B[k=g*8+j][n=m]) ----
  const int tq = t0 + wq * 32 + m;
  const float* qp = dq + ((size_t)tq * BATCH + b) * HDIM;
  f16x8 qh[16];
#pragma unroll
  for (int kb = 0; kb < 16; ++kb) {
    int h = kb * 16 + g * 8;
    float4 f0 = *(const float4*)(qp + h);
    float4 f1 = *(const float4*)(qp + h + 4);
    float xs[8] = {f0.x, f0.y, f0.z, f0.w, f1.x, f1.y, f1.z, f1.w};
    u16x8 hb;
#pragma unroll
    for (int j = 0; j < 8; ++j)
      hb[j] = __builtin_bit_cast(u16, (_Float16)xs[j]);
    qh[kb] = __builtin_bit_cast(f16x8, hb);
  }

  f32x16 ctx[8];
#pragma unroll
  for (int ht = 0; ht < 8; ++ht) ctx[ht] = (f32x16)(0.0f);
  float dsum = 0.0f;
  bf16x8 pa0 = {}, pa1 = {};     // P fragments for the pending PV (registers)

  // ---- staging: wave wv owns 8 KB of a pair's 32 KB stage ----
  // wv 0,1: KH chunk 2p | wv 2,3: VT 2p | wv 4,5: KH 2p+1 | wv 6,7: VT 2p+1
  const bool isVT  = (wv >> 1) & 1;
  const int  choff = wv >> 2;
  const int  subbase = (wv & 1) * 8;
  const u16* srcArr = isVT ? VT : KH;
  auto stage = [&](int p) {                 // stage pair p
    int ckk = 2 * p + choff;
    int ktile = 2 * (p & 1) + choff;        // K: 2 pair-sets
    int vtile = (p % 3) * 2 + choff;        // V: 3 pair-sets
    size_t tb = ((size_t)b * NCHUNK + ckk) * TILE_U16;
    u16* dst = isVT ? &VTs[vtile][0] : &KHs[ktile][0];
#pragma unroll
    for (int i = 0; i < 8; ++i) {
      int sub = subbase + i;
      __builtin_amdgcn_global_load_lds(
          (gp1_t)(const void*)&srcArr[tb + (size_t)sub * 512 + lane * 8],
          (lp3_t)(void*)&dst[sub * 512], 16, 0, 0);
    }
  };

  // QK^T as S^T (m=s, n=t) for pair p, fp16, two independent chains
  auto qk = [&](int p, f32x16& a0, f32x16& a1) {
    int kt = 2 * (p & 1) + grp;
#pragma unroll
    for (int kb = 0; kb < 16; kb += 2) {
      f16x8 k0 = __builtin_bit_cast(f16x8, *(const u16x8*)&KHs[kt][kb * 512 + lane * 8]);
      f16x8 k1 = __builtin_bit_cast(f16x8, *(const u16x8*)&KHs[kt][(kb + 1) * 512 + lane * 8]);
      a0 = __builtin_amdgcn_mfma_f32_32x32x16_f16(k0, qh[kb], a0, 0, 0, 0);
      a1 = __builtin_amdgcn_mfma_f32_32x32x16_f16(k1, qh[kb + 1], a1, 0, 0, 0);
    }
  };

  // PV for pair p using register P fragments pa0/pa1
  auto pv = [&](int p) {
    int vt_ = (p % 3) * 2 + grp;
#pragma unroll
    for (int ht = 0; ht < 8; ++ht) {
      bf16x8 v0 = __builtin_bit_cast(bf16x8, *(const u16x8*)&VTs[vt_][(ht * 2) * 512 + lane * 8]);
      bf16x8 v1 = __builtin_bit_cast(bf16x8, *(const u16x8*)&VTs[vt_][(ht * 2 + 1) * 512 + lane * 8]);
      ctx[ht] = __builtin_amdgcn_mfma_f32_32x32x16_bf16(pa0, v0, ctx[ht], 0, 0, 0);
      ctx[ht] = __builtin_amdgcn_mfma_f32_32x32x16_bf16(pa1, v1, ctx[ht], 0, 0, 0);
    }
  };

  // exp(s-128) -> dsum; cvt_pk + permlane32_swap builds PV A-frags (T12).
  auto softmax_pack = [&](const f32x16& a0, const f32x16& a1) {
    float pf[16];
#pragma unroll
    for (int r = 0; r < 16; ++r) {
      pf[r] = __expf(a0[r] + a1[r] - 128.0f);
      dsum += pf[r];
    }
    u32 c[8];
#pragma unroll
    for (int q = 0; q < 8; ++q)
      asm("v_cvt_pk_bf16_f32 %0, %1, %2"
          : "=v"(c[q]) : "v"(pf[2 * q]), "v"(pf[2 * q + 1]));
    asm("v_permlane32_swap_b32 %0, %1" : "+v"(c[0]), "+v"(c[2]));
    asm("v_permlane32_swap_b32 %0, %1" : "+v"(c[1]), "+v"(c[3]));
    asm("v_permlane32_swap_b32 %0, %1" : "+v"(c[4]), "+v"(c[6]));
    asm("v_permlane32_swap_b32 %0, %1" : "+v"(c[5]), "+v"(c[7]));
    u32x4 w0 = {c[0], c[1], c[2], c[3]};
    u32x4 w1 = {c[4], c[5], c[6], c[7]};
    pa0 = __builtin_bit_cast(bf16x8, w0);
    pa1 = __builtin_bit_cast(bf16x8, w1);
  };

  // ---- prologue: stage pairs 0,1; QK_0 + SM_0 ----
  stage(0);
  stage(1);
  asm volatile("s_waitcnt vmcnt(8)" ::: "memory");  // pair 0 landed; pair 1 in flight
  __builtin_amdgcn_s_barrier();
  {
    f32x16 a0 = (f32x16)(0.0f), a1 = (f32x16)(0.0f);
    qk(0, a0, a1);
    softmax_pack(a0, a1);
  }

  // ---- main loop: QK_{j+1} || PV_j, one barrier per iter ----
  for (int j = 0; j < 32; ++j) {
    asm volatile("s_waitcnt vmcnt(0)" ::: "memory"); // stage(j+1) landed
    __builtin_amdgcn_s_barrier();
    if (j < 30) stage(j + 2);

    f32x16 a0 = (f32x16)(0.0f), a1 = (f32x16)(0.0f);
    __builtin_amdgcn_s_setprio(1);
    if (j < 31) qk(j + 1, a0, a1);   // independent of PV below
    pv(j);                           // consumes pa0/pa1 from previous SM
    __builtin_amdgcn_s_setprio(0);
    if (j < 31) softmax_pack(a0, a1);  // overlaps in-flight PV MFMAs
  }

  // ---- combine the two source-halves (exact: same exp offset) ----
  dsum += __shfl_xor(dsum, 32, 64);   // per-lane: partial denom for t = m
  __syncthreads();                     // full drain once; bufs reusable

  // exchange regions (32 KB per target-group) carved from KHs/VTs
  float* exch = (wq == 0) ? (float*)&KHs[0][0]
              : (wq == 1) ? (float*)&KHs[2][0]
              : (wq == 2) ? (float*)&VTs[0][0]
                          : (float*)&VTs[2][0];
  float* dex = (float*)&VTs[4][0];   // denom exchange (1 KB)

  if (grp == 1) {
    // layout [r4][ht][lane][4]: b128, 2-way banks (free)
#pragma unroll
    for (int r4 = 0; r4 < 4; ++r4)
#pragma unroll
      for (int ht = 0; ht < 8; ++ht) {
        f32x4 v = {ctx[ht][r4 * 4], ctx[ht][r4 * 4 + 1],
                   ctx[ht][r4 * 4 + 2], ctx[ht][r4 * 4 + 3]};
        *(f32x4*)&exch[r4 * 2048 + ht * 256 + lane * 4] = v;
      }
    dex[wq * 64 + lane] = dsum;
  }
  __syncthreads();

  if (grp == 0) {
    float dB = dex[wq * 64 + lane];
    float inv = 1.0f / (dsum + dB);
#pragma unroll
    for (int r4 = 0; r4 < 4; ++r4)
#pragma unroll
      for (int ht = 0; ht < 8; ++ht) {
        f32x4 v = *(const f32x4*)&exch[r4 * 2048 + ht * 256 + lane * 4];
        ctx[ht][r4 * 4]     += v[0];
        ctx[ht][r4 * 4 + 1] += v[1];
        ctx[ht][r4 * 4 + 2] += v[2];
        ctx[ht][r4 * 4 + 3] += v[3];
      }
#pragma unroll
    for (int r = 0; r < 16; ++r) {
      int tl = (r & 3) + 8 * (r >> 2) + 4 * g;
      float rinv = __shfl(inv, tl, 64);
      int t = t0 + wq * 32 + tl;
      float* op = out + ((size_t)t * BATCH + b) * HDIM + m;
#pragma unroll
      for (int ht = 0; ht < 8; ++ht)
        op[ht * 32] = ctx[ht][r] * rinv;
    }
  }
}

extern "C" void kernel_launch(void* const* d_in, const int* in_sizes, int n_in,
                              void* d_out, int out_size, void* d_ws, size_t ws_size,
                              hipStream_t stream) {
  const float* e  = (const float*)d_in[0];  // out_e [2048, 16, 512]
  const float* dq = (const float*)d_in[1];  // out_d [2048, 16, 256]
  float* out = (float*)d_out;               // [2048, 16, 256]
  u16* KH = (u16*)d_ws;                                 // fp16 bits, 16 MB
  u16* VT = KH + (size_t)NTILES * TILE_U16;             // bf16 bits, 16 MB
  prepass_kernel<<<dim3(PREBLK), dim3(256), 0, stream>>>(e, KH, VT);
  attn_main_kernel<<<dim3(BATCH * (SEQ / TTILE)), dim3(512), 0, stream>>>(
      KH, VT, dq, out);
}